// Round 2
// 111.942 us; speedup vs baseline: 1.0029x; 1.0029x over previous
//
#include <hip/hip_runtime.h>

// PopulationLayer: lateral = pa @ (W with zeroed diag); v_new = exp(-0.1)*v + ext - lateral;
// out = (v_new > threshold) ? 1 : 0   (straight-through forward == hard)
//
// Output is BINARY -> absmax 0.02 means zero decision flips allowed.
// fp64 accumulation everywhere -> matched fp64 numpy ref to ~1e-13 (absmax 0.0 in R1-R4).
//
// R5/R6: ZERO-WORKSPACE version (R6 = resubmit of R5 after infra-level
// "container failed twice"; source audited, no OOB / no capture-unsafe calls).
// rocprof (R0) showed the timed region dominated by 256 MiB fillBufferAligned
// dispatches (~41 us each @ ~6.5 TB/s) = harness re-poisoning d_ws. Our
// compute is only ~15-20 us. Fold the 4 MiB fp64 partial buffer INTO the
// 4 MiB output buffer with a stripe-local layout:
//   partial(k, c) lives at double-index k*4096 + ((c&~3)>>1) + (c&1) + ((c>>1)&1)*2048
//   -> float rows {2k, 2k+1}, float cols {c&~3 .. c|3}  (inside c's 16-col stripe)
// Stage 2 (one block per 16-col stripe) reduces ONLY its own stripe's
// partials, then overwrites ONLY its own stripe's out region -> no races.
// d_ws is never touched.

#define PP 4096
#define BB 256

using f4 = __attribute__((ext_vector_type(4))) float;

constexpr int ROWS_PER_CHUNK = 32;
constexpr int NCHUNK = PP / ROWS_PER_CHUNK;   // 128
constexpr int COLS_PER_TILE = 1024;           // 256 thr * 4 cols
constexpr int NTILE = PP / COLS_PER_TILE;     // 4
constexpr int STRIPE = 16;                    // cols per stage-2 block
constexpr int NSTRIPE = PP / STRIPE;          // 256

// Stage 1: deterministic partial sums into the OUTPUT buffer (as doubles).
// grid = NTILE*NCHUNK = 512 blocks, 256 thr. Each thread owns 4 adjacent
// columns (float4 W load), 32 rows, fully unrolled.
__global__ __launch_bounds__(256)
void lateral_partial(const float* __restrict__ w, const float* __restrict__ pa,
                     double* __restrict__ pd) {
    const int tile = blockIdx.x & (NTILE - 1);
    const int rch  = blockIdx.x >> 2;               // NTILE == 4
    const int c    = tile * COLS_PER_TILE + (int)threadIdx.x * 4;
    const int r0   = rch * ROWS_PER_CHUNK;
    double a0 = 0.0, a1 = 0.0, a2 = 0.0, a3 = 0.0;
#pragma unroll
    for (int k = 0; k < ROWS_PER_CHUNK; ++k) {
        const int i = r0 + k;
        const double p = (double)pa[i];             // block-uniform -> scalar load
        const f4 wv = *reinterpret_cast<const f4*>(w + (size_t)i * PP + c);
        a0 += p * (double)wv.x;
        a1 += p * (double)wv.y;
        a2 += p * (double)wv.z;
        a3 += p * (double)wv.w;
    }
    // (k, cols c..c+1) -> float row 2k ; (k, cols c+2..c+3) -> float row 2k+1
    const size_t b = (size_t)rch * PP + (c >> 1);   // double index
    *reinterpret_cast<double2*>(pd + b)          = make_double2(a0, a1);
    *reinterpret_cast<double2*>(pd + b + PP / 2) = make_double2(a2, a3);
}

// Stage 2: fused reduce + diag-fix + LIF spike. One block per 16-col stripe,
// 256 thr. Reads its stripe's 128 partials/col (all inside the out-region it
// owns), reduces in LDS, then overwrites the same region with spikes.
// NOTE: pd/out alias the same buffer -> no __restrict__ on either.
__global__ __launch_bounds__(256)
void reduce_spike(const double* pd, const float* __restrict__ w,
                  const float* __restrict__ pa, const float* __restrict__ ext,
                  const float* __restrict__ v, const float* __restrict__ thr,
                  float* out) {
    __shared__ double sh[256];
    __shared__ double lat[STRIPE];
    const int t  = (int)threadIdx.x;
    const int c0 = (int)blockIdx.x * STRIPE;
    const int cj = t & (STRIPE - 1);                // col within stripe
    const int g  = t >> 4;                          // 16 chunk-groups
    const int c  = c0 + cj;
    const size_t off = (size_t)(((c & ~3) >> 1) + (c & 1) + ((c >> 1) & 1) * (PP / 2));
    double s = 0.0;
#pragma unroll
    for (int k = 0; k < NCHUNK / 16; ++k)           // 8 chunks per group
        s += pd[(size_t)(g * 8 + k) * PP + off];
    sh[t] = s;
    __syncthreads();
    if (t < 128) sh[t] += sh[t + 128];
    __syncthreads();
    if (t < 64)  sh[t] += sh[t + 64];
    __syncthreads();
    if (t < 32)  sh[t] += sh[t + 32];
    __syncthreads();
    if (t < 16) {
        const double r = sh[t] + sh[t + 16];
        const int cc = c0 + t;
        // remove self-connection: full sum included pa[cc]*W[cc,cc]
        lat[t] = r - (double)pa[cc] * (double)w[(size_t)cc * (PP + 1)];
    }
    __syncthreads();
    // spike: 256 rows x 16 cols per block; thread = 4 rows x 4 cols (float4)
    const int q    = t & 3;                         // float4 slot within stripe
    const int rowg = t >> 2;                        // 64 row-groups x 4 rows
    const double dec = 0.90483741803595952;         // exp(-0.1) in fp64
    const double l0 = lat[q * 4 + 0], l1 = lat[q * 4 + 1];
    const double l2 = lat[q * 4 + 2], l3 = lat[q * 4 + 3];
#pragma unroll
    for (int i = 0; i < 4; ++i) {
        const int r = rowg * 4 + i;
        const size_t idx = (size_t)r * PP + c0 + q * 4;
        const f4 e  = *reinterpret_cast<const f4*>(ext + idx);
        const f4 vv = *reinterpret_cast<const f4*>(v + idx);
        const f4 th = *reinterpret_cast<const f4*>(thr + idx);
        f4 o;
        o.x = (dec * (double)vv.x + (double)e.x - l0 > (double)th.x) ? 1.0f : 0.0f;
        o.y = (dec * (double)vv.y + (double)e.y - l1 > (double)th.y) ? 1.0f : 0.0f;
        o.z = (dec * (double)vv.z + (double)e.z - l2 > (double)th.z) ? 1.0f : 0.0f;
        o.w = (dec * (double)vv.w + (double)e.w - l3 > (double)th.w) ? 1.0f : 0.0f;
        *reinterpret_cast<f4*>(out + idx) = o;
    }
}

extern "C" void kernel_launch(void* const* d_in, const int* in_sizes, int n_in,
                              void* d_out, int out_size, void* d_ws, size_t ws_size,
                              hipStream_t stream) {
    const float* ext = (const float*)d_in[0];   // [B,P]
    const float* w   = (const float*)d_in[1];   // [P,P]
    const float* pa  = (const float*)d_in[2];   // [P]
    const float* v   = (const float*)d_in[3];   // [B,P]
    const float* thr = (const float*)d_in[4];   // [B,P]
    float* out = (float*)d_out;
    double* pd = (double*)d_out;  // out reused as partial scratch (exactly 4 MiB)

    lateral_partial<<<NTILE * NCHUNK, 256, 0, stream>>>(w, pa, pd);
    reduce_spike<<<NSTRIPE, 256, 0, stream>>>(pd, w, pa, ext, v, thr, out);
}